// Round 3
// baseline (124.356 us; speedup 1.0000x reference)
//
#include <hip/hip_runtime.h>
#include <math.h>

// 192 blocks x 1024 threads, 6 per batch element (n = bid&31, r = bid>>5).
// NO atomic RMWs anywhere: all cross-block exchange is single-writer relaxed
// agent-scope atomic stores/loads, ordered by per-block release-stored MAGIC
// flags. Flag polls are RELAXED (no per-poll buffer_inv): all cross-block data
// (p1/p2/ssum/pairs) is read via relaxed agent atomic loads that bypass the
// non-coherent caches; writers release-store the flag after the data stores.
// ws is 0xAA-poisoned before every call -> flags start != MAGIC, no memset.
//
// R1: conv2 restructured (bordered pitch-40 bf16 tile, slot=input-channel
//     split, b32 pair reads, cross-slot LDS reduce): conflicts 829K->235K.
// R2: relaxed polls + head-tail compression (fused single fc1 pass).
// R3: SYMMETRIC TAIL. Occupancy (22%) showed ~half the runtime was the
//     32-head-block tail. Now all 6 blocks of an n (same XCD: bid%8==n%8)
//     split fc1 by column slice (~172 cols = 88KB each), compute qfull+sterm
//     redundantly, and post partial fc2 results via a 4th flag round; head
//     sums 6 pairs. Prefetch moved into the BN1-wait window (all blocks,
//     own slice + full w_rel) so the L2 pull is 24-block-parallel per XCD.

#define N_BATCH 32
#define C_OUT 24
#define NBLK 192
#define MAGIC 0x13579BDFu
#define AGENT __HIP_MEMORY_SCOPE_AGENT
#define PITCH 40                 // ushorts per row (row 0 and col 0 are zero border)
#define NROWS 33                 // rows 0..32 (row = oh+1)
#define CHSZ (PITCH * NROWS)     // 1320 ushorts per channel plane

__device__ __forceinline__ float aload(const float* p) {
  return __hip_atomic_load(p, __ATOMIC_RELAXED, AGENT);
}
__device__ __forceinline__ void astore(float* p, float v) {
  __hip_atomic_store(p, v, __ATOMIC_RELAXED, AGENT);
}
__device__ __forceinline__ void waitflag(const unsigned* f) {
  while (__hip_atomic_load(f, __ATOMIC_RELAXED, AGENT) != MAGIC)
    __builtin_amdgcn_s_sleep(1);
}

__global__ __launch_bounds__(1024) void fused_kernel(
    const float* __restrict__ img, const float* __restrict__ ques,
    const float* __restrict__ c1w, const float* __restrict__ c1b,
    const float* __restrict__ g1,  const float* __restrict__ bt1,
    const float* __restrict__ c2w, const float* __restrict__ c2b,
    const float* __restrict__ g2,  const float* __restrict__ bt2,
    const float* __restrict__ w_rel, const float* __restrict__ b_rel,
    const float* __restrict__ w_fc1, const float* __restrict__ b_fc1,
    const float* __restrict__ w_fc2, const float* __restrict__ b_fc2,
    float* __restrict__ out,
    unsigned* __restrict__ flags1, unsigned* __restrict__ flags2,
    unsigned* __restrict__ flags3, unsigned* __restrict__ flags4,
    float* __restrict__ p1, float* __restrict__ p2,
    float* __restrict__ ssum, float* __restrict__ pairs) {
  const int t = threadIdx.x;
  const int bid = blockIdx.x;
  const int lane = t & 63, wid = t >> 6;
  const int n = bid & 31;
  const int r = bid >> 5;            // 0..5, owns channels r*4..r*4+3

  // fc1 column slice for this block: float4-groups [g0, g0+gcnt), cols 4*g0..
  const int g0 = r * 43 - (r == 5 ? 1 : 0);   // 0,43,86,129,172,214
  const int gcnt = (r < 4) ? 43 : 42;         // 4*43+2*42 = 256 groups = 1024 cols

  __shared__ unsigned short y1u[24 * CHSZ];   // ~61.9 KB, bf16, bordered+pitched
  __align__(16) __shared__ float red[5120];   // conv2 reduce / fc1 reduce
  __shared__ float s_a[C_OUT], s_b[C_OUT];    // BN1 scale/shift
  __shared__ float a2[4], b2[4];              // BN2 (this block's 4 channels)
  __shared__ float chS[16], chS2[16];
  __shared__ float qpart[1024];
  __shared__ float qfull[128];
  __shared__ float s_s[26];
  __shared__ float s_coef[128];

  // zero the borders (row 0 fully; col 0 of rows 1..32) before first use
  if (t < 24 * PITCH) {
    int ch = t / PITCH;
    y1u[ch * CHSZ + (t - ch * PITCH)] = 0;            // row 0
  }
  if (t < 768)
    y1u[(t >> 5) * CHSZ + ((t & 31) + 1) * PITCH] = 0; // col 0, rows 1..32

  // ---------------- phase 1: conv1, 1 pixel/thread, all 24 co ----------------
  {
    int oh = t >> 5, ow = t & 31;
    float win[27];
    #pragma unroll
    for (int ci = 0; ci < 3; ci++)
      #pragma unroll
      for (int kh = 0; kh < 3; kh++) {
        int ih = oh * 2 - 1 + kh;
        #pragma unroll
        for (int kw = 0; kw < 3; kw++) {
          int iw = ow * 2 - 1 + kw;
          win[ci * 9 + kh * 3 + kw] =
              (ih >= 0 && iw >= 0) ? img[(n * 3 + ci) * 4096 + ih * 64 + iw] : 0.f;
        }
      }
    #pragma unroll
    for (int co = 0; co < C_OUT; co++) {
      float acc = c1b[co];
      #pragma unroll
      for (int q = 0; q < 27; q++) acc += win[q] * c1w[co * 27 + q];
      unsigned bits = __float_as_uint(acc);
      unsigned rr = (bits + 0x7FFFu + ((bits >> 16) & 1u)) >> 16;  // rne
      y1u[co * CHSZ + (oh + 1) * PITCH + (ow + 1)] = (unsigned short)rr;
    }
  }
  __syncthreads();

  // stage-1 stats: only r==0 blocks write p1 + flags1[n]
  if (r == 0) {
    if (t < 768) {
      int ch = t >> 5, l = t & 31;
      float s = 0.f, s2 = 0.f;
      #pragma unroll
      for (int i = 0; i < 32; i++) {
        float x = __uint_as_float(
            (unsigned)y1u[ch * CHSZ + (i + 1) * PITCH + (l + 1)] << 16);
        s += x; s2 += x * x;
      }
      #pragma unroll
      for (int off = 16; off > 0; off >>= 1) {
        s += __shfl_down(s, off, 32);
        s2 += __shfl_down(s2, off, 32);
      }
      if (l == 0) {
        astore(&p1[ch * 32 + n], s);
        astore(&p1[768 + ch * 32 + n], s2);
      }
    }
    __syncthreads();
    if (t == 0)
      __hip_atomic_store(&flags1[n], MAGIC, __ATOMIC_RELEASE, AGENT);
  }

  // ---- L2 prefetch (all blocks, fills the BN1-wait window) ----
  // own w_fc1 slice: 128 rows x 8 lines of 32 floats (covers 172 cols + slack)
  {
    float pf = 0.f;
    {
      int row = t >> 3, l = t & 7;
      int col = g0 * 4 + l * 32;
      col = col < 1024 ? col : 1023;
      pf += w_fc1[row * 1024 + col];
    }
    if (t < 720) pf += w_rel[t * 32];     // all of w_rel (180*128 floats)
    if (t < 64)  pf += w_fc2[t * 32];     // 8 KB
    if (t < 32)  pf += b_fc1[t * 32];     // 4 KB
    asm volatile("" :: "v"(pf));          // keep loads alive
  }

  // ---------------- wait BN1 stats + finalize (all blocks) ----------------
  if (t < 32) waitflag(&flags1[t]);
  __syncthreads();
  if (t < 768) {
    int ch = t >> 5, j = t & 31;
    float s = aload(&p1[ch * 32 + j]);
    float s2 = aload(&p1[768 + ch * 32 + j]);
    #pragma unroll
    for (int off = 16; off > 0; off >>= 1) {
      s += __shfl_down(s, off, 32);
      s2 += __shfl_down(s2, off, 32);
    }
    if (j == 0) {
      float mu = s * (1.f / 32768.f);
      float var = s2 * (1.f / 32768.f) - mu * mu;
      float a = rsqrtf(var + 1e-5f) * g1[ch];
      s_a[ch] = a;
      s_b[ch] = bt1[ch] - mu * a;
    }
  }
  __syncthreads();

  // ---------------- phase 2: conv2 ----------------
  const int px = t & 255;
  const int slot = t >> 8;                         // 0..3, wave-uniform
  const int co2 = r * 4 + slot;
  float acc2;
  {
    const int o2h = px >> 4, o2w = px & 15;
    float accq[4] = {0.f, 0.f, 0.f, 0.f};
    const int ci0 = slot * 6;
    #pragma unroll
    for (int cc = 0; cc < 6; cc++) {
      const int ci = ci0 + cc;
      const float a1 = s_a[ci], b1 = s_b[ci];
      const unsigned* chp = (const unsigned*)(y1u + ci * CHSZ);
      #pragma unroll
      for (int kh = 0; kh < 3; kh++) {
        const int row = o2h * 2 + kh;              // = ih+1, in 0..32
        const unsigned* pr = chp + row * (PITCH / 2);
        unsigned w0 = pr[o2w];                     // cols 2*o2w, 2*o2w+1
        unsigned w1 = pr[o2w + 1];                 // cols 2*o2w+2
        float x0 = __uint_as_float(w0 << 16);
        float x1 = __uint_as_float(w0 & 0xffff0000u);
        float x2 = __uint_as_float(w1 << 16);
        x0 = fmaxf(fmaf(x0, a1, b1), 0.f);
        x1 = fmaxf(fmaf(x1, a1, b1), 0.f);
        x2 = fmaxf(fmaf(x2, a1, b1), 0.f);
        if (row == 0) { x0 = 0.f; x1 = 0.f; x2 = 0.f; }  // top zero-pad
        if (o2w == 0) x0 = 0.f;                           // left zero-pad
        #pragma unroll
        for (int co = 0; co < 4; co++) {
          const float* wp = c2w + ((r * 4 + co) * C_OUT + ci) * 9 + kh * 3;
          accq[co] = fmaf(x0, wp[0], accq[co]);
          accq[co] = fmaf(x1, wp[1], accq[co]);
          accq[co] = fmaf(x2, wp[2], accq[co]);
        }
      }
    }
    #pragma unroll
    for (int q = 0; q < 4; q++) red[(slot * 256 + px) * 5 + q] = accq[q];
  }
  __syncthreads();
  {
    acc2 = c2b[co2];
    #pragma unroll
    for (int s = 0; s < 4; s++) acc2 += red[(s * 256 + px) * 5 + slot];
  }
  // per-block stage-2 partials (this n, 4 channels), single-writer
  {
    float s = acc2, s2 = acc2 * acc2;
    #pragma unroll
    for (int off = 32; off > 0; off >>= 1) {
      s += __shfl_down(s, off, 64);
      s2 += __shfl_down(s2, off, 64);
    }
    if (lane == 0) { chS[slot * 4 + (wid & 3)] = s; chS2[slot * 4 + (wid & 3)] = s2; }
  }
  __syncthreads();
  if (t < 4) {
    float s = chS[t * 4] + chS[t * 4 + 1] + chS[t * 4 + 2] + chS[t * 4 + 3];
    float s2 = chS2[t * 4] + chS2[t * 4 + 1] + chS2[t * 4 + 2] + chS2[t * 4 + 3];
    astore(&p2[(r * 4 + t) * 32 + n], s);
    astore(&p2[768 + (r * 4 + t) * 32 + n], s2);
  }
  __syncthreads();
  if (t == 0)
    __hip_atomic_store(&flags2[bid], MAGIC, __ATOMIC_RELEASE, AGENT);

  // ---- qfull (all blocks, redundant; fills the BN2-wait window) ----
  {
    int m = t & 127, g = t >> 7;
    const float* qv = ques + n * 128;
    float q = 0.f;
    for (int k = g * 16; k < g * 16 + 16; k++)
      q += qv[k] * w_rel[(52 + k) * 128 + m];
    qpart[t] = q;
  }
  __syncthreads();
  if (t < 128) {
    float q = b_rel[t];
    #pragma unroll
    for (int g = 0; g < 8; g++) q += qpart[g * 128 + t];
    qfull[t] = 65536.f * q;
  }

  // ---------------- wait BN2 stats for our r-group, finalize 4 channels -------
  if (t < 32) waitflag(&flags2[r * 32 + t]);
  __syncthreads();
  if (t < 128) {
    int c4 = t >> 5, j = t & 31;
    float s = aload(&p2[(r * 4 + c4) * 32 + j]);
    float s2 = aload(&p2[768 + (r * 4 + c4) * 32 + j]);
    #pragma unroll
    for (int off = 16; off > 0; off >>= 1) {
      s += __shfl_down(s, off, 32);
      s2 += __shfl_down(s2, off, 32);
    }
    if (j == 0) {
      float mu = s * (1.f / 8192.f);
      float var = s2 * (1.f / 8192.f) - mu * mu;
      float a = rsqrtf(var + 1e-5f) * g2[r * 4 + c4];
      a2[c4] = a;
      b2[c4] = bt2[r * 4 + c4] - mu * a;
    }
  }
  __syncthreads();

  // relu(bn2) spatial sums -> ssum[n*24+co], single-writer
  {
    float v = acc2 * a2[slot] + b2[slot];
    v = v > 0.f ? v : 0.f;
    #pragma unroll
    for (int off = 32; off > 0; off >>= 1) v += __shfl_down(v, off, 64);
    if (lane == 0) chS[slot * 4 + (wid & 3)] = v;
  }
  __syncthreads();
  if (t < 4)
    astore(&ssum[n * C_OUT + r * 4 + t],
           chS[t * 4] + chS[t * 4 + 1] + chS[t * 4 + 2] + chS[t * 4 + 3]);
  __syncthreads();
  if (t == 0)
    __hip_atomic_store(&flags3[bid], MAGIC, __ATOMIC_RELEASE, AGENT);

  // ---------------- phase 3: ALL blocks, split by fc1 column slice ----------
  if (t < 6 && t != r) waitflag(&flags3[t * 32 + n]);
  __syncthreads();
  if (t < C_OUT) s_s[t] = aload(&ssum[n * C_OUT + t]);
  if (t == 24 || t == 25) {
    float cs = 0.f;
    for (int i = 0; i < 16; i++) cs += -1.f + 2.f * (float)i / 15.f;
    s_s[t] = 16.f * cs;
  }
  __syncthreads();

  // sterm partials across all 1024 threads: col = t&127, d-range by g = t>>7
  {
    int col = t & 127, g = t >> 7;
    float p = 0.f;
    #pragma unroll
    for (int dd = 0; dd < 4; dd++) {
      int d = g + dd * 8;
      if (d < 26)
        p += s_s[d] * (w_rel[d * 128 + col] + w_rel[(26 + d) * 128 + col]);
    }
    qpart[t] = p;
  }
  __syncthreads();
  if (t < 128) {
    float sterm = 0.f;
    #pragma unroll
    for (int g = 0; g < 8; g++) sterm += qpart[g * 128 + t];
    s_coef[t] = qfull[t] + 256.f * sterm;
  }
  __syncthreads();

  // fc1 over this block's slice: wave wid owns m-range wid*8..+7, lane = group
  {
    const int gi = lane, mseg = wid;
    if (gi < gcnt) {
      const float4* wp = (const float4*)w_fc1 + (g0 + gi);
      float4 acc = make_float4(0.f, 0.f, 0.f, 0.f);
      #pragma unroll
      for (int k = 0; k < 8; k++) {
        int m = mseg * 8 + k;
        float c = s_coef[m];
        float4 w = wp[m * 256];
        acc.x += c * w.x; acc.y += c * w.y; acc.z += c * w.z; acc.w += c * w.w;
      }
      ((float4*)red)[mseg * 43 + gi] = acc;   // red[mseg*172 + gi*4 ..+3]
    }
  }
  __syncthreads();
  float a0 = 0.f, a1 = 0.f;
  if (t < gcnt * 4) {
    const int gcol = g0 * 4 + t;
    float h = b_fc1[gcol];
    #pragma unroll
    for (int mseg = 0; mseg < 16; mseg++) h += red[mseg * 172 + t];
    h = h > 0.f ? h : 0.f;
    a0 = h * w_fc2[2 * gcol];
    a1 = h * w_fc2[2 * gcol + 1];
  }
  __syncthreads();
  {
    #pragma unroll
    for (int off = 32; off > 0; off >>= 1) {
      a0 += __shfl_down(a0, off, 64);
      a1 += __shfl_down(a1, off, 64);
    }
    if (lane == 0) { chS[wid] = a0; chS2[wid] = a1; }
  }
  __syncthreads();
  if (t == 0) {
    float b0 = 0.f, b1v = 0.f;
    #pragma unroll
    for (int i = 0; i < 16; i++) { b0 += chS[i]; b1v += chS2[i]; }
    if (r != 0) {
      astore(&pairs[n * 12 + r * 2 + 0], b0);
      astore(&pairs[n * 12 + r * 2 + 1], b1v);
      __hip_atomic_store(&flags4[bid], MAGIC, __ATOMIC_RELEASE, AGENT);
    } else {
      chS[0] = b0; chS2[0] = b1v;   // keep own partial for the final sum
    }
  }
  if (r != 0) return;

  // head: wait 5 sibling fc2 partials, sum, write out
  if (t >= 1 && t < 6) waitflag(&flags4[t * 32 + n]);
  __syncthreads();
  if (t == 0) {
    float b0 = chS[0], b1v = chS2[0];
    #pragma unroll
    for (int i = 1; i < 6; i++) {
      b0 += aload(&pairs[n * 12 + i * 2 + 0]);
      b1v += aload(&pairs[n * 12 + i * 2 + 1]);
    }
    out[n * 2 + 0] = b0 + b_fc2[0];
    out[n * 2 + 1] = b1v + b_fc2[1];
  }
}

extern "C" void kernel_launch(void* const* d_in, const int* in_sizes, int n_in,
                              void* d_out, int out_size, void* d_ws, size_t ws_size,
                              hipStream_t stream) {
  const float* image   = (const float*)d_in[0];
  const float* ques    = (const float*)d_in[1];
  const float* conv1_w = (const float*)d_in[2];
  const float* conv1_b = (const float*)d_in[3];
  const float* bn1_g   = (const float*)d_in[4];
  const float* bn1_b   = (const float*)d_in[5];
  const float* conv2_w = (const float*)d_in[6];
  const float* conv2_b = (const float*)d_in[7];
  const float* bn2_g   = (const float*)d_in[8];
  const float* bn2_b   = (const float*)d_in[9];
  const float* w_rel   = (const float*)d_in[10];
  const float* b_rel   = (const float*)d_in[11];
  const float* w_fc1   = (const float*)d_in[12];
  const float* b_fc1   = (const float*)d_in[13];
  const float* w_fc2   = (const float*)d_in[14];
  const float* b_fc2   = (const float*)d_in[15];
  float* out = (float*)d_out;

  unsigned* flags1 = (unsigned*)d_ws;          // 32
  unsigned* flags2 = flags1 + 32;              // 192
  unsigned* flags3 = flags2 + 192;             // 192
  unsigned* flags4 = flags3 + 192;             // 192  (total 608 uints)
  float* p1    = (float*)d_ws + 608;           // 1536
  float* p2    = p1 + 1536;                    // 1536
  float* ssum  = p2 + 1536;                    // 768
  float* pairs = ssum + 768;                   // 384

  fused_kernel<<<NBLK, 1024, 0, stream>>>(
      image, ques, conv1_w, conv1_b, bn1_g, bn1_b, conv2_w, conv2_b,
      bn2_g, bn2_b, w_rel, b_rel, w_fc1, b_fc1, w_fc2, b_fc2,
      out, flags1, flags2, flags3, flags4, p1, p2, ssum, pairs);
}